// Round 25
// baseline (147.202 us; speedup 1.0000x reference)
//
#include <hip/hip_runtime.h>
#include <hip/hip_bf16.h>
#include <math.h>

#define BH 64
#define NN 8192
#define DD 64
#define MM 32

#define NROWS (BH*NN)            // 524288
#define NORMC 0.35355339059327379f   // 64^-0.25
#define RATIO 0.17677669529663689f   // 32^-0.5
#define EPSK  1e-4f
#define DIAGC 0.0625f                // 0.5 * 64^-0.5

#define CPB 32                   // chunks per batch
#define CHUNK 256                // rows per chunk (8 waves x 32 rows)
#define K12_BLOCKS (BH*CPB)      // 2048 blocks x 512 threads

#define ESTR 44                  // E' staging row stride in ushorts (88B = 22
                                 // banks -> 16 distinct start banks for lr)
#define WSTR (2*32*ESTR)         // per-wave staging: hi+lo, 32 rows

typedef __attribute__((ext_vector_type(8))) short short8;
typedef __attribute__((ext_vector_type(4))) float f32x4;

union FragU { uint4 u; short8 s; };

// packed fp32x2 -> bf16x2 (round-nearest-even, HW conversion)
__device__ __forceinline__ unsigned pkbf(float a, float b) {
  union { __hip_bfloat162 b2; unsigned u; } r;
  r.b2 = __float22bfloat162_rn(make_float2(a, b));
  return r.u;
}
// packed lo-residuals given the packed hi word (hi values via bit-mask)
__device__ __forceinline__ unsigned pklo(float a, float b, unsigned h) {
  const float ha = __uint_as_float(h << 16);
  const float hb = __uint_as_float(h & 0xffff0000u);
  return pkbf(a - ha, b - hb);
}
// 8 fp32 -> hi/lo bf16x8 fragments (split: x = hi + lo)
__device__ __forceinline__ void cvt8(const float* f, FragU& hi, FragU& lo) {
  unsigned hw[4], lw[4];
  #pragma unroll
  for (int p = 0; p < 4; ++p) {
    hw[p] = pkbf(f[2*p], f[2*p+1]);
    lw[p] = pklo(f[2*p], f[2*p+1], hw[p]);
  }
  hi.u = make_uint4(hw[0], hw[1], hw[2], hw[3]);
  lo.u = make_uint4(lw[0], lw[1], lw[2], lw[3]);
}

#define MFMA(a,b,c) __builtin_amdgcn_mfma_f32_16x16x32_bf16((a),(b),(c),0,0,0)

__device__ __forceinline__ float wave_max(float v) {
  #pragma unroll
  for (int off = 32; off > 0; off >>= 1)
    v = fmaxf(v, __shfl_down(v, off, 64));
  return v;
}

// inline proj B-fragments (per-lane; proj is 8KB, L2-resident after warmup)
__device__ __forceinline__ void load_proj_frags(
    const float* __restrict__ proj, int lr, int lg,
    FragU (&pbH)[2][2], FragU (&pbL)[2][2]) {
  #pragma unroll
  for (int mt = 0; mt < 2; ++mt)
    #pragma unroll
    for (int ks = 0; ks < 2; ++ks) {
      float f[8];
      #pragma unroll
      for (int j = 0; j < 8; ++j)
        f[j] = proj[(mt*16 + lr)*DD + ks*32 + lg*8 + j];
      cvt8(f, pbH[mt][ks], pbL[mt][ks]);
    }
}

// read a bf16x8 fragment from 8B-aligned staging (2 x ds_read_b64)
__device__ __forceinline__ uint4 read_frag64(const ushort* p) {
  const uint2* p2 = (const uint2*)p;
  const uint2 a = p2[0], b = p2[1];
  return make_uint4(a.x, a.y, b.x, b.y);
}

// ---------------- K12: FUSED — dash MFMA -> E' (LDS bf16) -> kv MFMA --------
// R25 = R24 with conflict-free E' staging stride (40 -> 44 ushorts): start
// bank = (22*lr + ...)%32 covers 16 distinct banks for the 16 lr lanes
// (was 8 with stride 40 -> 2-way aliasing on every b128 read/write; 5.5M
// conflict cycles/dispatch, ~6.5 cy per LDS op on phase B's serial chain).
// 88B rows are 8B-aligned -> fragments read as 2 x ds_read_b64.
__global__ __launch_bounds__(512, 4) void k12_kv(
    const float* __restrict__ k, const float* __restrict__ v,
    const float* __restrict__ proj,
    float* __restrict__ kvPart, float* __restrict__ ksPart,
    float* __restrict__ vsPart, float* __restrict__ partialMax)
{
  __shared__ float red[11272];     // 45088 B: 8 x WSTR staging, then reductions
  const int t = threadIdx.x;       // 0..511
  const int w = t >> 6, l = t & 63;
  const int lr = l & 15, lg = l >> 4;
  const int blk = blockIdx.x;
  const int b = blk >> 5, c = blk & (CPB - 1);
  const size_t nrow0 = (size_t)b * NN + (size_t)c * CHUNK + (size_t)w * 32;

  ushort* eh = (ushort*)red + w * WSTR;   // [32 m][ESTR] hi
  ushort* el = eh + 32*ESTR;              // [32 m][ESTR] lo

  FragU pbH[2][2], pbL[2][2];      // persistent proj fragments (inline build)
  load_proj_frags(proj, lr, lg, pbH, pbL);

  f32x4 accK[2][4];
  #pragma unroll
  for (int mt = 0; mt < 2; ++mt)
    #pragma unroll
    for (int dt = 0; dt < 4; ++dt)
      accK[mt][dt] = (f32x4){0.f, 0.f, 0.f, 0.f};
  float ksacc0 = 0.f, ksacc1 = 0.f;
  float vsum[4] = {0.f, 0.f, 0.f, 0.f};
  float tmax = -3.4e38f;

  // ---- phase A: E' for this wave's 32 rows (MFMA dash), staged to LDS
  #pragma unroll
  for (int rt = 0; rt < 2; ++rt) {
    float sq = 0.f;
    f32x4 a0 = {0.f,0.f,0.f,0.f}, a1 = {0.f,0.f,0.f,0.f};
    #pragma unroll
    for (int ks = 0; ks < 2; ++ks) {
      const float4* src = (const float4*)(k + (nrow0 + rt*16 + lr)*DD + ks*32 + lg*8);
      float4 x0 = src[0], x1 = src[1];
      float qv[8] = {x0.x,x0.y,x0.z,x0.w, x1.x,x1.y,x1.z,x1.w};
      #pragma unroll
      for (int j = 0; j < 8; ++j) sq += qv[j]*qv[j];
      FragU aH, aL; cvt8(qv, aH, aL);     // live only inside this ks

      a0 = MFMA(aL.s, pbH[0][ks].s, a0);
      a0 = MFMA(aH.s, pbL[0][ks].s, a0);
      a0 = MFMA(aH.s, pbH[0][ks].s, a0);
      a1 = MFMA(aL.s, pbH[1][ks].s, a1);
      a1 = MFMA(aH.s, pbL[1][ks].s, a1);
      a1 = MFMA(aH.s, pbH[1][ks].s, a1);
    }
    sq += __shfl_xor(sq, 16, 64);
    sq += __shfl_xor(sq, 32, 64);
    float e0v[4], e1v[4];
    #pragma unroll
    for (int reg = 0; reg < 4; ++reg) {
      const float diag = DIAGC * __shfl(sq, lg*4 + reg, 64);
      const float d0 = a0[reg] * NORMC;
      const float d1 = a1[reg] * NORMC;
      tmax = fmaxf(tmax, fmaxf(d0, d1));
      e0v[reg] = __expf(d0 - diag);
      e1v[reg] = __expf(d1 - diag);
      ksacc0 += e0v[reg];                // col m = lr
      ksacc1 += e1v[reg];                // col m = lr+16
    }
    const int nloc = rt*16 + lg*4;       // 4 consecutive ushorts, 4B-aligned
    const unsigned h00 = pkbf(e0v[0], e0v[1]), h01 = pkbf(e0v[2], e0v[3]);
    const unsigned l00 = pklo(e0v[0], e0v[1], h00), l01 = pklo(e0v[2], e0v[3], h01);
    const unsigned h10 = pkbf(e1v[0], e1v[1]), h11 = pkbf(e1v[2], e1v[3]);
    const unsigned l10 = pklo(e1v[0], e1v[1], h10), l11 = pklo(e1v[2], e1v[3], h11);
    *(unsigned*)(eh + lr*ESTR      + nloc)     = h00;
    *(unsigned*)(eh + lr*ESTR      + nloc + 2) = h01;
    *(unsigned*)(el + lr*ESTR      + nloc)     = l00;
    *(unsigned*)(el + lr*ESTR      + nloc + 2) = l01;
    *(unsigned*)(eh + (lr+16)*ESTR + nloc)     = h10;
    *(unsigned*)(eh + (lr+16)*ESTR + nloc + 2) = h11;
    *(unsigned*)(el + (lr+16)*ESTR + nloc)     = l10;
    *(unsigned*)(el + (lr+16)*ESTR + nloc + 2) = l11;
  }

  // ---- phase B: kv += E'^T x v via MFMA (A from LDS, B from global)
  #pragma unroll
  for (int dt = 0; dt < 4; ++dt) {
    float vv[8];
    #pragma unroll
    for (int j = 0; j < 8; ++j)
      vv[j] = v[(nrow0 + lg*8 + j)*DD + dt*16 + lr];
    vsum[dt] += vv[0]+vv[1]+vv[2]+vv[3]+vv[4]+vv[5]+vv[6]+vv[7];
    FragU bHv, bLv; cvt8(vv, bHv, bLv);
    #pragma unroll
    for (int mt = 0; mt < 2; ++mt) {
      FragU aHk, aLk;
      aHk.u = read_frag64(eh + (mt*16 + lr)*ESTR + lg*8);
      aLk.u = read_frag64(el + (mt*16 + lr)*ESTR + lg*8);
      accK[mt][dt] = MFMA(aLk.s, bHv.s, accK[mt][dt]);
      accK[mt][dt] = MFMA(aHk.s, bLv.s, accK[mt][dt]);
      accK[mt][dt] = MFMA(aHk.s, bHv.s, accK[mt][dt]);
    }
  }

  // ---- epilogue: wave reductions, then two-stage cross-wave reduction
  tmax = wave_max(tmax);
  ksacc0 += __shfl_xor(ksacc0, 16, 64);
  ksacc0 += __shfl_xor(ksacc0, 32, 64);
  ksacc1 += __shfl_xor(ksacc1, 16, 64);
  ksacc1 += __shfl_xor(ksacc1, 32, 64);
  #pragma unroll
  for (int dt = 0; dt < 4; ++dt) {
    vsum[dt] += __shfl_xor(vsum[dt], 16, 64);
    vsum[dt] += __shfl_xor(vsum[dt], 32, 64);
  }
  __syncthreads();                 // all staging reads done; red reusable
  if (w < 4) {
    #pragma unroll
    for (int mt = 0; mt < 2; ++mt)
      #pragma unroll
      for (int dt = 0; dt < 4; ++dt)
        #pragma unroll
        for (int reg = 0; reg < 4; ++reg)
          red[((mt*16 + lg*4 + reg)*64 + dt*16 + lr)*4 + w] = accK[mt][dt][reg];
  }
  if (l == 0) red[8192 + w] = tmax;
  __syncthreads();
  if (w >= 4) {
    #pragma unroll
    for (int mt = 0; mt < 2; ++mt)
      #pragma unroll
      for (int dt = 0; dt < 4; ++dt)
        #pragma unroll
        for (int reg = 0; reg < 4; ++reg)
          red[((mt*16 + lg*4 + reg)*64 + dt*16 + lr)*4 + (w-4)] += accK[mt][dt][reg];
  }
  __syncthreads();
  if (t == 0) {
    float mx = red[8192];
    #pragma unroll
    for (int i = 1; i < 8; ++i) mx = fmaxf(mx, red[8192+i]);
    partialMax[blk] = mx;
  }
  #pragma unroll
  for (int ii = 0; ii < 4; ++ii) {
    const int o = t + 512 * ii;
    const float4 r4 = *(const float4*)&red[o*4];
    kvPart[(size_t)blk * 2048 + o] = r4.x + r4.y + r4.z + r4.w;
  }
  __syncthreads();
  if (l < 16) {
    red[w*32 + lr]        = ksacc0;
    red[w*32 + 16 + lr]   = ksacc1;
    #pragma unroll
    for (int dt = 0; dt < 4; ++dt)
      red[256 + w*64 + dt*16 + lr] = vsum[dt];
  }
  __syncthreads();
  if (t < 32) {
    float s = 0.f;
    #pragma unroll
    for (int ww = 0; ww < 8; ++ww) s += red[ww*32 + t];
    ksPart[blk*32 + t] = s;
  }
  if (t < 64) {
    float s = 0.f;
    #pragma unroll
    for (int ww = 0; ww < 8; ++ww) s += red[256 + ww*64 + t];
    vsPart[blk*64 + t] = s;
  }
}

// ---------------- K2b_sum: gmax (redundant per block) + parallel reduction --
__global__ __launch_bounds__(256) void k2b_sum(
    const float* __restrict__ partialMax,
    const float* __restrict__ kvPart, const float* __restrict__ ksPart,
    const float* __restrict__ vsPart,
    float* __restrict__ kvF, float* __restrict__ ksF)
{
  __shared__ float vsumL[64];
  __shared__ float wred[4];
  const int blk = blockIdx.x;
  const int b = blk >> 3, seg = blk & 7;
  const int t = threadIdx.x;
  float mx = -3.4e38f;
  for (int i = t; i < K12_BLOCKS; i += 256) mx = fmaxf(mx, partialMax[i]);
  mx = wave_max(mx);
  if ((t & 63) == 0) wred[t >> 6] = mx;
  if (t < 64) {
    float s = 0.f;
    #pragma unroll 4
    for (int c = 0; c < CPB; ++c)
      s += vsPart[(b * CPB + c) * 64 + t];
    vsumL[t] = s;
  }
  __syncthreads();
  const float scale =
      __expf(-fmaxf(fmaxf(wred[0], wred[1]), fmaxf(wred[2], wred[3])));
  const int o = seg * 256 + t;
  float s = 0.f;
  #pragma unroll 4
  for (int c = 0; c < CPB; ++c)
    s += kvPart[((size_t)(b * CPB + c)) * 2048 + o];
  kvF[b * 2048 + o] = RATIO * (scale * s + EPSK * vsumL[o & 63]);
  if (seg == 0 && t < 32) {
    float ks = 0.f;
    #pragma unroll 4
    for (int c = 0; c < CPB; ++c)
      ks += ksPart[(b * CPB + c) * 32 + t];
    ksF[b * 32 + t] = RATIO * (scale * ks + EPSK * (float)NN);
  }
}

// ---------------- K2c: kvF -> kv B-fragments --------------------------------
__global__ __launch_bounds__(256) void k2c_frag(
    const float* __restrict__ kvF,
    uint4* __restrict__ kfH, uint4* __restrict__ kfL)
{
  __shared__ float kvL[2048];
  const int b = blockIdx.x, t = threadIdx.x;
  #pragma unroll
  for (int ii = 0; ii < 8; ++ii)
    kvL[t + 256*ii] = kvF[b*2048 + t + 256*ii];
  __syncthreads();
  const int l = t & 63, dt = t >> 6;
  const int lr = l & 15, lg = l >> 4;
  float f[8];
  #pragma unroll
  for (int j = 0; j < 8; ++j)
    f[j] = kvL[(lg*8 + j)*64 + dt*16 + lr];
  FragU hi, lo; cvt8(f, hi, lo);
  kfH[(b*4 + dt)*64 + l] = hi.u;
  kfL[(b*4 + dt)*64 + l] = lo.u;
}

// ---------------- K3: dash MFMA -> softmax -> num MFMA (barrier-free) -------
__global__ __launch_bounds__(256, 4) void k3_out(
    const float* __restrict__ q, const float* __restrict__ proj,
    const uint4* __restrict__ kfH, const uint4* __restrict__ kfL,
    const float* __restrict__ ksF, float* __restrict__ out)
{
  __shared__ float dashL[256][36];   // fp32 dash; reused per-row as packed pstar
  __shared__ float ssqL[256][4];
  const int t = threadIdx.x;
  const int w = t >> 6, l = t & 63;
  const int lr = l & 15, lg = l >> 4;
  const int b = blockIdx.x >> 5;
  const size_t rowBase = (size_t)blockIdx.x * 256;
  const int wrb = w * 64;

  FragU pbH[2][2], pbL[2][2];
  load_proj_frags(proj, lr, lg, pbH, pbL);

  // phase A
  #pragma unroll
  for (int rt = 0; rt < 4; ++rt) {
    const int rrow = wrb + rt*16 + lr;
    f32x4 acc0 = {0.f,0.f,0.f,0.f}, acc1 = {0.f,0.f,0.f,0.f};
    float sq = 0.f;
    #pragma unroll
    for (int ks = 0; ks < 2; ++ks) {
      const float4* src = (const float4*)(q + (rowBase + rrow)*DD + ks*32 + lg*8);
      float4 a0 = src[0], a1 = src[1];
      float qv[8] = {a0.x,a0.y,a0.z,a0.w, a1.x,a1.y,a1.z,a1.w};
      #pragma unroll
      for (int j = 0; j < 8; ++j) sq += qv[j]*qv[j];
      FragU aH, aL; cvt8(qv, aH, aL);
      acc0 = MFMA(aL.s, pbH[0][ks].s, acc0);
      acc0 = MFMA(aH.s, pbL[0][ks].s, acc0);
      acc0 = MFMA(aH.s, pbH[0][ks].s, acc0);
      acc1 = MFMA(aL.s, pbH[1][ks].s, acc1);
      acc1 = MFMA(aH.s, pbL[1][ks].s, acc1);
      acc1 = MFMA(aH.s, pbH[1][ks].s, acc1);
    }
    ssqL[rrow][lg] = sq;
    #pragma unroll
    for (int reg = 0; reg < 4; ++reg) {
      dashL[wrb + rt*16 + lg*4 + reg][lr]      = acc0[reg];
      dashL[wrb + rt*16 + lg*4 + reg][16 + lr] = acc1[reg];
    }
  }

  // softmax phase: thread t owns row t (same wave as its stripe: no barrier)
  {
    float dv[32];
    const float4* dr = (const float4*)&dashL[t][0];
    #pragma unroll
    for (int i = 0; i < 8; ++i) {
      float4 v4 = dr[i];
      dv[4*i]=v4.x; dv[4*i+1]=v4.y; dv[4*i+2]=v4.z; dv[4*i+3]=v4.w;
    }
    const float ssq = ssqL[t][0]+ssqL[t][1]+ssqL[t][2]+ssqL[t][3];
    float mx = -3.4e38f;
    #pragma unroll
    for (int m = 0; m < MM; ++m) { dv[m] *= NORMC; mx = fmaxf(mx, dv[m]); }
    const float sub = DIAGC * ssq + mx;
    const float* __restrict__ ksb = ksF + b * 32;
    float den = 0.f;
    #pragma unroll
    for (int m = 0; m < MM; ++m) {
      dv[m] = RATIO * (__expf(dv[m] - sub) + EPSK);
      den = fmaf(dv[m], ksb[m], den);
    }
    const float inv = 1.0f / den;
    unsigned hiw[16], low[16];
    #pragma unroll
    for (int u = 0; u < 16; ++u) {
      const float x0 = dv[2*u] * inv, x1 = dv[2*u+1] * inv;
      hiw[u] = pkbf(x0, x1);
      low[u] = pklo(x0, x1, hiw[u]);
    }
    uint4* pr = (uint4*)&dashL[t][0];   // overwrite own row only
    pr[0] = make_uint4(hiw[0],hiw[1],hiw[2],hiw[3]);
    pr[1] = make_uint4(hiw[4],hiw[5],hiw[6],hiw[7]);
    pr[2] = make_uint4(hiw[8],hiw[9],hiw[10],hiw[11]);
    pr[3] = make_uint4(hiw[12],hiw[13],hiw[14],hiw[15]);
    pr[4] = make_uint4(low[0],low[1],low[2],low[3]);
    pr[5] = make_uint4(low[4],low[5],low[6],low[7]);
    pr[6] = make_uint4(low[8],low[9],low[10],low[11]);
    pr[7] = make_uint4(low[12],low[13],low[14],low[15]);
  }

  // phase B: out = pstar · kv (K=32, one k-step, 3 comp terms)
  FragU kbH[4], kbL[4];
  #pragma unroll
  for (int dt = 0; dt < 4; ++dt) {
    kbH[dt].u = kfH[(b*4 + dt)*64 + l];
    kbL[dt].u = kfL[(b*4 + dt)*64 + l];
  }
  #pragma unroll
  for (int rt = 0; rt < 4; ++rt) {
    const uint4* pr = (const uint4*)&dashL[wrb + rt*16 + lr][0];
    FragU aH, aL;
    aH.u = pr[lg];
    aL.u = pr[4 + lg];
    #pragma unroll
    for (int dt = 0; dt < 4; ++dt) {
      f32x4 o = {0.f,0.f,0.f,0.f};
      o = MFMA(aL.s, kbH[dt].s, o);
      o = MFMA(aH.s, kbL[dt].s, o);
      o = MFMA(aH.s, kbH[dt].s, o);
      float* ob = out + (rowBase + wrb + rt*16 + lg*4)*DD + dt*16 + lr;
      ob[0]      = o[0];
      ob[DD]     = o[1];
      ob[2*DD]   = o[2];
      ob[3*DD]   = o[3];
    }
  }
}

// ---------------- host ------------------------------------------------------
extern "C" void kernel_launch(void* const* d_in, const int* in_sizes, int n_in,
                              void* d_out, int out_size, void* d_ws, size_t ws_size,
                              hipStream_t stream) {
  const float* q    = (const float*)d_in[0];
  const float* k    = (const float*)d_in[1];
  const float* v    = (const float*)d_in[2];
  const float* proj = (const float*)d_in[3];
  float* out = (float*)d_out;
  float* ws  = (float*)d_ws;

  float*    partialMax = ws;                       // 2048
  float*    kvPart     = ws + 4096;                // 2048*2048
  float*    ksPart     = kvPart + 4194304;         // 2048*32
  float*    vsPart     = ksPart + 65536;           // 2048*64
  float*    ksF        = vsPart + 131072;          // 64*32 (pad 2048)
  float*    kvF        = ksF + 2048;               // 64*2048
  unsigned* kfH        = (unsigned*)(kvF + 131072);// 64*4*64 uint4 = 65536 words
  unsigned* kfL        = kfH + 65536;              // 65536

  k12_kv<<<K12_BLOCKS, 512, 0, stream>>>(k, v, proj,
                                         kvPart, ksPart, vsPart, partialMax);
  k2b_sum<<<BH*8, 256, 0, stream>>>(partialMax, kvPart, ksPart, vsPart,
                                    kvF, ksF);
  k2c_frag<<<BH, 256, 0, stream>>>(kvF, (uint4*)kfH, (uint4*)kfL);
  k3_out<<<NROWS / 256, 256, 0, stream>>>(q, proj,
                                          (uint4*)kfH, (uint4*)kfL, ksF, out);
}

// Round 26
// 145.084 us; speedup vs baseline: 1.0146x; 1.0146x over previous
//
#include <hip/hip_runtime.h>
#include <hip/hip_bf16.h>
#include <math.h>

#define BH 64
#define NN 8192
#define DD 64
#define MM 32

#define NROWS (BH*NN)            // 524288
#define NORMC 0.35355339059327379f   // 64^-0.25
#define RATIO 0.17677669529663689f   // 32^-0.5
#define EPSK  1e-4f
#define DIAGC 0.0625f                // 0.5 * 64^-0.5

#define CPB 32                   // chunks per batch
#define CHUNK 256                // rows per chunk (8 waves x 32 rows)
#define K12_BLOCKS (BH*CPB)      // 2048 blocks x 512 threads

typedef __attribute__((ext_vector_type(8))) short short8;
typedef __attribute__((ext_vector_type(4))) float f32x4;

union FragU { uint4 u; short8 s; };

// packed fp32x2 -> bf16x2 (round-nearest-even, HW conversion)
__device__ __forceinline__ unsigned pkbf(float a, float b) {
  union { __hip_bfloat162 b2; unsigned u; } r;
  r.b2 = __float22bfloat162_rn(make_float2(a, b));
  return r.u;
}
// packed lo-residuals given the packed hi word (hi values via bit-mask)
__device__ __forceinline__ unsigned pklo(float a, float b, unsigned h) {
  const float ha = __uint_as_float(h << 16);
  const float hb = __uint_as_float(h & 0xffff0000u);
  return pkbf(a - ha, b - hb);
}
// 8 fp32 -> hi/lo bf16x8 fragments (split: x = hi + lo)
__device__ __forceinline__ void cvt8(const float* f, FragU& hi, FragU& lo) {
  unsigned hw[4], lw[4];
  #pragma unroll
  for (int p = 0; p < 4; ++p) {
    hw[p] = pkbf(f[2*p], f[2*p+1]);
    lw[p] = pklo(f[2*p], f[2*p+1], hw[p]);
  }
  hi.u = make_uint4(hw[0], hw[1], hw[2], hw[3]);
  lo.u = make_uint4(lw[0], lw[1], lw[2], lw[3]);
}

#define MFMA(a,b,c) __builtin_amdgcn_mfma_f32_16x16x32_bf16((a),(b),(c),0,0,0)

__device__ __forceinline__ float wave_max(float v) {
  #pragma unroll
  for (int off = 32; off > 0; off >>= 1)
    v = fmaxf(v, __shfl_down(v, off, 64));
  return v;
}

// inline proj B-fragments (per-lane; proj is 8KB, L2-resident after warmup)
__device__ __forceinline__ void load_proj_frags(
    const float* __restrict__ proj, int lr, int lg,
    FragU (&pbH)[2][2], FragU (&pbL)[2][2]) {
  #pragma unroll
  for (int mt = 0; mt < 2; ++mt)
    #pragma unroll
    for (int ks = 0; ks < 2; ++ks) {
      float f[8];
      #pragma unroll
      for (int j = 0; j < 8; ++j)
        f[j] = proj[(mt*16 + lr)*DD + ks*32 + lg*8 + j];
      cvt8(f, pbH[mt][ks], pbL[mt][ks]);
    }
}

// ---------------- K12: FUSED — dash MFMA -> E' (LDS bf16) -> kv MFMA --------
// R26 = R24 exactly (best measured: 146.0 us). R25's stride-44 staging was
// neutral (most "conflict" cycles are the inherent 4-access/bank floor of
// the 128-bank-access read shape, not aliasing).
__global__ __launch_bounds__(512, 4) void k12_kv(
    const float* __restrict__ k, const float* __restrict__ v,
    const float* __restrict__ proj,
    float* __restrict__ kvPart, float* __restrict__ ksPart,
    float* __restrict__ vsPart, float* __restrict__ partialMax)
{
  __shared__ float red[10240];     // 40960 B: 8x5KB staging, then reductions
  const int t = threadIdx.x;       // 0..511
  const int w = t >> 6, l = t & 63;
  const int lr = l & 15, lg = l >> 4;
  const int blk = blockIdx.x;
  const int b = blk >> 5, c = blk & (CPB - 1);
  const size_t nrow0 = (size_t)b * NN + (size_t)c * CHUNK + (size_t)w * 32;

  ushort* eh = (ushort*)red + w * 2560;   // [32 m][40] hi  (2560B/wave)
  ushort* el = eh + 1280;                 // [32 m][40] lo

  FragU pbH[2][2], pbL[2][2];      // persistent proj fragments (inline build)
  load_proj_frags(proj, lr, lg, pbH, pbL);

  f32x4 accK[2][4];
  #pragma unroll
  for (int mt = 0; mt < 2; ++mt)
    #pragma unroll
    for (int dt = 0; dt < 4; ++dt)
      accK[mt][dt] = (f32x4){0.f, 0.f, 0.f, 0.f};
  float ksacc0 = 0.f, ksacc1 = 0.f;
  float vsum[4] = {0.f, 0.f, 0.f, 0.f};
  float tmax = -3.4e38f;

  // ---- phase A: E' for this wave's 32 rows (MFMA dash), staged to LDS
  #pragma unroll
  for (int rt = 0; rt < 2; ++rt) {
    float sq = 0.f;
    f32x4 a0 = {0.f,0.f,0.f,0.f}, a1 = {0.f,0.f,0.f,0.f};
    #pragma unroll
    for (int ks = 0; ks < 2; ++ks) {
      const float4* src = (const float4*)(k + (nrow0 + rt*16 + lr)*DD + ks*32 + lg*8);
      float4 x0 = src[0], x1 = src[1];
      float qv[8] = {x0.x,x0.y,x0.z,x0.w, x1.x,x1.y,x1.z,x1.w};
      #pragma unroll
      for (int j = 0; j < 8; ++j) sq += qv[j]*qv[j];
      FragU aH, aL; cvt8(qv, aH, aL);     // live only inside this ks

      a0 = MFMA(aL.s, pbH[0][ks].s, a0);
      a0 = MFMA(aH.s, pbL[0][ks].s, a0);
      a0 = MFMA(aH.s, pbH[0][ks].s, a0);
      a1 = MFMA(aL.s, pbH[1][ks].s, a1);
      a1 = MFMA(aH.s, pbL[1][ks].s, a1);
      a1 = MFMA(aH.s, pbH[1][ks].s, a1);
    }
    sq += __shfl_xor(sq, 16, 64);
    sq += __shfl_xor(sq, 32, 64);
    float e0v[4], e1v[4];
    #pragma unroll
    for (int reg = 0; reg < 4; ++reg) {
      const float diag = DIAGC * __shfl(sq, lg*4 + reg, 64);
      const float d0 = a0[reg] * NORMC;
      const float d1 = a1[reg] * NORMC;
      tmax = fmaxf(tmax, fmaxf(d0, d1));
      e0v[reg] = __expf(d0 - diag);
      e1v[reg] = __expf(d1 - diag);
      ksacc0 += e0v[reg];                // col m = lr
      ksacc1 += e1v[reg];                // col m = lr+16
    }
    const int nloc = rt*16 + lg*4;       // 4 consecutive ushorts, 4B-aligned
    const unsigned h00 = pkbf(e0v[0], e0v[1]), h01 = pkbf(e0v[2], e0v[3]);
    const unsigned l00 = pklo(e0v[0], e0v[1], h00), l01 = pklo(e0v[2], e0v[3], h01);
    const unsigned h10 = pkbf(e1v[0], e1v[1]), h11 = pkbf(e1v[2], e1v[3]);
    const unsigned l10 = pklo(e1v[0], e1v[1], h10), l11 = pklo(e1v[2], e1v[3], h11);
    *(unsigned*)(eh + lr*40      + nloc)     = h00;
    *(unsigned*)(eh + lr*40      + nloc + 2) = h01;
    *(unsigned*)(el + lr*40      + nloc)     = l00;
    *(unsigned*)(el + lr*40      + nloc + 2) = l01;
    *(unsigned*)(eh + (lr+16)*40 + nloc)     = h10;
    *(unsigned*)(eh + (lr+16)*40 + nloc + 2) = h11;
    *(unsigned*)(el + (lr+16)*40 + nloc)     = l10;
    *(unsigned*)(el + (lr+16)*40 + nloc + 2) = l11;
  }

  // ---- phase B: kv += E'^T x v via MFMA (A from LDS, B from global)
  #pragma unroll
  for (int dt = 0; dt < 4; ++dt) {
    float vv[8];
    #pragma unroll
    for (int j = 0; j < 8; ++j)
      vv[j] = v[(nrow0 + lg*8 + j)*DD + dt*16 + lr];
    vsum[dt] += vv[0]+vv[1]+vv[2]+vv[3]+vv[4]+vv[5]+vv[6]+vv[7];
    FragU bHv, bLv; cvt8(vv, bHv, bLv);
    #pragma unroll
    for (int mt = 0; mt < 2; ++mt) {
      FragU aHk, aLk;
      aHk.u = *(const uint4*)(eh + (mt*16 + lr)*40 + lg*8);
      aLk.u = *(const uint4*)(el + (mt*16 + lr)*40 + lg*8);
      accK[mt][dt] = MFMA(aLk.s, bHv.s, accK[mt][dt]);
      accK[mt][dt] = MFMA(aHk.s, bLv.s, accK[mt][dt]);
      accK[mt][dt] = MFMA(aHk.s, bHv.s, accK[mt][dt]);
    }
  }

  // ---- epilogue: wave reductions, then two-stage cross-wave reduction
  tmax = wave_max(tmax);
  ksacc0 += __shfl_xor(ksacc0, 16, 64);
  ksacc0 += __shfl_xor(ksacc0, 32, 64);
  ksacc1 += __shfl_xor(ksacc1, 16, 64);
  ksacc1 += __shfl_xor(ksacc1, 32, 64);
  #pragma unroll
  for (int dt = 0; dt < 4; ++dt) {
    vsum[dt] += __shfl_xor(vsum[dt], 16, 64);
    vsum[dt] += __shfl_xor(vsum[dt], 32, 64);
  }
  __syncthreads();                 // all staging reads done; red reusable
  if (w < 4) {
    #pragma unroll
    for (int mt = 0; mt < 2; ++mt)
      #pragma unroll
      for (int dt = 0; dt < 4; ++dt)
        #pragma unroll
        for (int reg = 0; reg < 4; ++reg)
          red[((mt*16 + lg*4 + reg)*64 + dt*16 + lr)*4 + w] = accK[mt][dt][reg];
  }
  if (l == 0) red[8192 + w] = tmax;
  __syncthreads();
  if (w >= 4) {
    #pragma unroll
    for (int mt = 0; mt < 2; ++mt)
      #pragma unroll
      for (int dt = 0; dt < 4; ++dt)
        #pragma unroll
        for (int reg = 0; reg < 4; ++reg)
          red[((mt*16 + lg*4 + reg)*64 + dt*16 + lr)*4 + (w-4)] += accK[mt][dt][reg];
  }
  __syncthreads();
  if (t == 0) {
    float mx = red[8192];
    #pragma unroll
    for (int i = 1; i < 8; ++i) mx = fmaxf(mx, red[8192+i]);
    partialMax[blk] = mx;
  }
  #pragma unroll
  for (int ii = 0; ii < 4; ++ii) {
    const int o = t + 512 * ii;
    const float4 r4 = *(const float4*)&red[o*4];
    kvPart[(size_t)blk * 2048 + o] = r4.x + r4.y + r4.z + r4.w;
  }
  __syncthreads();
  if (l < 16) {
    red[w*32 + lr]        = ksacc0;
    red[w*32 + 16 + lr]   = ksacc1;
    #pragma unroll
    for (int dt = 0; dt < 4; ++dt)
      red[256 + w*64 + dt*16 + lr] = vsum[dt];
  }
  __syncthreads();
  if (t < 32) {
    float s = 0.f;
    #pragma unroll
    for (int ww = 0; ww < 8; ++ww) s += red[ww*32 + t];
    ksPart[blk*32 + t] = s;
  }
  if (t < 64) {
    float s = 0.f;
    #pragma unroll
    for (int ww = 0; ww < 8; ++ww) s += red[256 + ww*64 + t];
    vsPart[blk*64 + t] = s;
  }
}

// ---------------- K2b_sum: gmax (redundant per block) + parallel reduction --
__global__ __launch_bounds__(256) void k2b_sum(
    const float* __restrict__ partialMax,
    const float* __restrict__ kvPart, const float* __restrict__ ksPart,
    const float* __restrict__ vsPart,
    float* __restrict__ kvF, float* __restrict__ ksF)
{
  __shared__ float vsumL[64];
  __shared__ float wred[4];
  const int blk = blockIdx.x;
  const int b = blk >> 3, seg = blk & 7;
  const int t = threadIdx.x;
  float mx = -3.4e38f;
  for (int i = t; i < K12_BLOCKS; i += 256) mx = fmaxf(mx, partialMax[i]);
  mx = wave_max(mx);
  if ((t & 63) == 0) wred[t >> 6] = mx;
  if (t < 64) {
    float s = 0.f;
    #pragma unroll 4
    for (int c = 0; c < CPB; ++c)
      s += vsPart[(b * CPB + c) * 64 + t];
    vsumL[t] = s;
  }
  __syncthreads();
  const float scale =
      __expf(-fmaxf(fmaxf(wred[0], wred[1]), fmaxf(wred[2], wred[3])));
  const int o = seg * 256 + t;
  float s = 0.f;
  #pragma unroll 4
  for (int c = 0; c < CPB; ++c)
    s += kvPart[((size_t)(b * CPB + c)) * 2048 + o];
  kvF[b * 2048 + o] = RATIO * (scale * s + EPSK * vsumL[o & 63]);
  if (seg == 0 && t < 32) {
    float ks = 0.f;
    #pragma unroll 4
    for (int c = 0; c < CPB; ++c)
      ks += ksPart[(b * CPB + c) * 32 + t];
    ksF[b * 32 + t] = RATIO * (scale * ks + EPSK * (float)NN);
  }
}

// ---------------- K2c: kvF -> kv B-fragments --------------------------------
__global__ __launch_bounds__(256) void k2c_frag(
    const float* __restrict__ kvF,
    uint4* __restrict__ kfH, uint4* __restrict__ kfL)
{
  __shared__ float kvL[2048];
  const int b = blockIdx.x, t = threadIdx.x;
  #pragma unroll
  for (int ii = 0; ii < 8; ++ii)
    kvL[t + 256*ii] = kvF[b*2048 + t + 256*ii];
  __syncthreads();
  const int l = t & 63, dt = t >> 6;
  const int lr = l & 15, lg = l >> 4;
  float f[8];
  #pragma unroll
  for (int j = 0; j < 8; ++j)
    f[j] = kvL[(lg*8 + j)*64 + dt*16 + lr];
  FragU hi, lo; cvt8(f, hi, lo);
  kfH[(b*4 + dt)*64 + l] = hi.u;
  kfL[(b*4 + dt)*64 + l] = lo.u;
}

// ---------------- K3: dash MFMA -> softmax -> num MFMA (barrier-free) -------
__global__ __launch_bounds__(256, 4) void k3_out(
    const float* __restrict__ q, const float* __restrict__ proj,
    const uint4* __restrict__ kfH, const uint4* __restrict__ kfL,
    const float* __restrict__ ksF, float* __restrict__ out)
{
  __shared__ float dashL[256][36];   // fp32 dash; reused per-row as packed pstar
  __shared__ float ssqL[256][4];
  const int t = threadIdx.x;
  const int w = t >> 6, l = t & 63;
  const int lr = l & 15, lg = l >> 4;
  const int b = blockIdx.x >> 5;
  const size_t rowBase = (size_t)blockIdx.x * 256;
  const int wrb = w * 64;

  FragU pbH[2][2], pbL[2][2];
  load_proj_frags(proj, lr, lg, pbH, pbL);

  // phase A
  #pragma unroll
  for (int rt = 0; rt < 4; ++rt) {
    const int rrow = wrb + rt*16 + lr;
    f32x4 acc0 = {0.f,0.f,0.f,0.f}, acc1 = {0.f,0.f,0.f,0.f};
    float sq = 0.f;
    #pragma unroll
    for (int ks = 0; ks < 2; ++ks) {
      const float4* src = (const float4*)(q + (rowBase + rrow)*DD + ks*32 + lg*8);
      float4 a0 = src[0], a1 = src[1];
      float qv[8] = {a0.x,a0.y,a0.z,a0.w, a1.x,a1.y,a1.z,a1.w};
      #pragma unroll
      for (int j = 0; j < 8; ++j) sq += qv[j]*qv[j];
      FragU aH, aL; cvt8(qv, aH, aL);
      acc0 = MFMA(aL.s, pbH[0][ks].s, acc0);
      acc0 = MFMA(aH.s, pbL[0][ks].s, acc0);
      acc0 = MFMA(aH.s, pbH[0][ks].s, acc0);
      acc1 = MFMA(aL.s, pbH[1][ks].s, acc1);
      acc1 = MFMA(aH.s, pbL[1][ks].s, acc1);
      acc1 = MFMA(aH.s, pbH[1][ks].s, acc1);
    }
    ssqL[rrow][lg] = sq;
    #pragma unroll
    for (int reg = 0; reg < 4; ++reg) {
      dashL[wrb + rt*16 + lg*4 + reg][lr]      = acc0[reg];
      dashL[wrb + rt*16 + lg*4 + reg][16 + lr] = acc1[reg];
    }
  }

  // softmax phase: thread t owns row t (same wave as its stripe: no barrier)
  {
    float dv[32];
    const float4* dr = (const float4*)&dashL[t][0];
    #pragma unroll
    for (int i = 0; i < 8; ++i) {
      float4 v4 = dr[i];
      dv[4*i]=v4.x; dv[4*i+1]=v4.y; dv[4*i+2]=v4.z; dv[4*i+3]=v4.w;
    }
    const float ssq = ssqL[t][0]+ssqL[t][1]+ssqL[t][2]+ssqL[t][3];
    float mx = -3.4e38f;
    #pragma unroll
    for (int m = 0; m < MM; ++m) { dv[m] *= NORMC; mx = fmaxf(mx, dv[m]); }
    const float sub = DIAGC * ssq + mx;
    const float* __restrict__ ksb = ksF + b * 32;
    float den = 0.f;
    #pragma unroll
    for (int m = 0; m < MM; ++m) {
      dv[m] = RATIO * (__expf(dv[m] - sub) + EPSK);
      den = fmaf(dv[m], ksb[m], den);
    }
    const float inv = 1.0f / den;
    unsigned hiw[16], low[16];
    #pragma unroll
    for (int u = 0; u < 16; ++u) {
      const float x0 = dv[2*u] * inv, x1 = dv[2*u+1] * inv;
      hiw[u] = pkbf(x0, x1);
      low[u] = pklo(x0, x1, hiw[u]);
    }
    uint4* pr = (uint4*)&dashL[t][0];   // overwrite own row only
    pr[0] = make_uint4(hiw[0],hiw[1],hiw[2],hiw[3]);
    pr[1] = make_uint4(hiw[4],hiw[5],hiw[6],hiw[7]);
    pr[2] = make_uint4(hiw[8],hiw[9],hiw[10],hiw[11]);
    pr[3] = make_uint4(hiw[12],hiw[13],hiw[14],hiw[15]);
    pr[4] = make_uint4(low[0],low[1],low[2],low[3]);
    pr[5] = make_uint4(low[4],low[5],low[6],low[7]);
    pr[6] = make_uint4(low[8],low[9],low[10],low[11]);
    pr[7] = make_uint4(low[12],low[13],low[14],low[15]);
  }

  // phase B: out = pstar · kv (K=32, one k-step, 3 comp terms)
  FragU kbH[4], kbL[4];
  #pragma unroll
  for (int dt = 0; dt < 4; ++dt) {
    kbH[dt].u = kfH[(b*4 + dt)*64 + l];
    kbL[dt].u = kfL[(b*4 + dt)*64 + l];
  }
  #pragma unroll
  for (int rt = 0; rt < 4; ++rt) {
    const uint4* pr = (const uint4*)&dashL[wrb + rt*16 + lr][0];
    FragU aH, aL;
    aH.u = pr[lg];
    aL.u = pr[4 + lg];
    #pragma unroll
    for (int dt = 0; dt < 4; ++dt) {
      f32x4 o = {0.f,0.f,0.f,0.f};
      o = MFMA(aL.s, kbH[dt].s, o);
      o = MFMA(aH.s, kbL[dt].s, o);
      o = MFMA(aH.s, kbH[dt].s, o);
      float* ob = out + (rowBase + wrb + rt*16 + lg*4)*DD + dt*16 + lr;
      ob[0]      = o[0];
      ob[DD]     = o[1];
      ob[2*DD]   = o[2];
      ob[3*DD]   = o[3];
    }
  }
}

// ---------------- host ------------------------------------------------------
extern "C" void kernel_launch(void* const* d_in, const int* in_sizes, int n_in,
                              void* d_out, int out_size, void* d_ws, size_t ws_size,
                              hipStream_t stream) {
  const float* q    = (const float*)d_in[0];
  const float* k    = (const float*)d_in[1];
  const float* v    = (const float*)d_in[2];
  const float* proj = (const float*)d_in[3];
  float* out = (float*)d_out;
  float* ws  = (float*)d_ws;

  float*    partialMax = ws;                       // 2048
  float*    kvPart     = ws + 4096;                // 2048*2048
  float*    ksPart     = kvPart + 4194304;         // 2048*32
  float*    vsPart     = ksPart + 65536;           // 2048*64
  float*    ksF        = vsPart + 131072;          // 64*32 (pad 2048)
  float*    kvF        = ksF + 2048;               // 64*2048
  unsigned* kfH        = (unsigned*)(kvF + 131072);// 64*4*64 uint4 = 65536 words
  unsigned* kfL        = kfH + 65536;              // 65536

  k12_kv<<<K12_BLOCKS, 512, 0, stream>>>(k, v, proj,
                                         kvPart, ksPart, vsPart, partialMax);
  k2b_sum<<<BH*8, 256, 0, stream>>>(partialMax, kvPart, ksPart, vsPart,
                                    kvF, ksF);
  k2c_frag<<<BH, 256, 0, stream>>>(kvF, (uint4*)kfH, (uint4*)kfL);
  k3_out<<<NROWS / 256, 256, 0, stream>>>(q, proj,
                                          (uint4*)kfH, (uint4*)kfL, ksF, out);
}